// Round 2
// baseline (1428.577 us; speedup 1.0000x reference)
//
#include <hip/hip_runtime.h>
#include <hip/hip_bf16.h>
#include <math.h>

typedef __hip_bfloat16 bf16;

__device__ __forceinline__ float b2f(bf16 v) { return __bfloat162float(v); }
__device__ __forceinline__ bf16 f2b(float f) { return __float2bfloat16(f); }
// bf16 pair packed in a uint (little-endian: elem0 = low 16 bits)
__device__ __forceinline__ float unpk_lo(unsigned u) { return __uint_as_float(u << 16); }
__device__ __forceinline__ float unpk_hi(unsigned u) { return __uint_as_float(u & 0xffff0000u); }
__device__ __forceinline__ unsigned pk2(float a, float b) {
    unsigned ua = __float_as_uint(a);
    unsigned ub = __float_as_uint(b);
    ua = (ua + 0x7fffu + ((ua >> 16) & 1u)) >> 16;   // RNE to bf16
    ub = (ub + 0x7fffu + ((ub >> 16) & 1u)) >> 16;
    return ua | (ub << 16);
}
__device__ __forceinline__ float gelu_exact(float x) {
    return 0.5f * x * (1.f + erff(x * 0.70710678118654752440f));
}

// ---------------------------------------------------------------------------
// Kernel 1: ctx = LN(context^T over EC=256) @ ctxp_w + ctxp_b -> (B,HW,64) bf16
// grid 1024 (= B * HW/64), block 256. Packed-bf16 LDS tile (32 KB) for the
// transposed coalesced staging of 256x64 column block.
// ---------------------------------------------------------------------------
__global__ __launch_bounds__(256) void k_ctx(const float* __restrict__ ctx,
                                             const float* __restrict__ g,
                                             const float* __restrict__ bb,
                                             const float* __restrict__ w,
                                             const float* __restrict__ pb,
                                             bf16* __restrict__ outp) {
    __shared__ unsigned tile[256][32];
    __shared__ float redS[8][64];
    __shared__ float redQ[8][64];
    __shared__ float s_mu[64], s_rs[64];
    const int t  = threadIdx.x;
    const int tx = t & 31;          // column pair (2tx, 2tx+1)
    const int ty = t >> 5;          // e-stripe 0..7
    const int b   = blockIdx.x >> 6;
    const int hw0 = (blockIdx.x & 63) << 6;
    const float* cbase = ctx + ((size_t)b * 256) * 4096 + hw0 + 2 * tx;
    float sa = 0.f, qa = 0.f, sb = 0.f, qb2 = 0.f;
    for (int e = ty; e < 256; e += 8) {
        float2 v = *(const float2*)(cbase + (size_t)e * 4096);
        tile[e][tx] = pk2(v.x, v.y);
        sa += v.x; qa += v.x * v.x;
        sb += v.y; qb2 += v.y * v.y;
    }
    redS[ty][2 * tx] = sa;  redS[ty][2 * tx + 1] = sb;
    redQ[ty][2 * tx] = qa;  redQ[ty][2 * tx + 1] = qb2;
    __syncthreads();
    if (t < 64) {
        float st = 0.f, qt = 0.f;
#pragma unroll
        for (int k = 0; k < 8; ++k) { st += redS[k][t]; qt += redQ[k][t]; }
        float mu = st * (1.f / 256.f);
        float var = qt * (1.f / 256.f) - mu * mu;
        s_mu[t] = mu;
        s_rs[t] = rsqrtf(var + 1e-5f);
    }
    __syncthreads();
    {
        float mu0 = s_mu[2 * tx], mu1 = s_mu[2 * tx + 1];
        float rs0 = s_rs[2 * tx], rs1 = s_rs[2 * tx + 1];
        for (int e = ty; e < 256; e += 8) {
            unsigned u = tile[e][tx];
            float ge = g[e], be = bb[e];
            float a0 = (unpk_lo(u) - mu0) * rs0 * ge + be;
            float a1 = (unpk_hi(u) - mu1) * rs1 * ge + be;
            tile[e][tx] = pk2(a0, a1);
        }
    }
    __syncthreads();
    // projection: column j = tx2 (hw), out channels ty2*16..+16
    const int tx2 = t & 63;
    const int ty2 = t >> 6;
    float acc[16];
#pragma unroll
    for (int q = 0; q < 16; ++q) acc[q] = pb[ty2 * 16 + q];
    for (int e = 0; e < 256; ++e) {
        unsigned u = tile[e][tx2 >> 1];
        float a = (tx2 & 1) ? unpk_hi(u) : unpk_lo(u);
        const float4* wv = (const float4*)(w + e * 64 + ty2 * 16);
        float4 w0 = wv[0], w1 = wv[1], w2v = wv[2], w3 = wv[3];
        acc[0]  += a * w0.x;  acc[1]  += a * w0.y;  acc[2]  += a * w0.z;  acc[3]  += a * w0.w;
        acc[4]  += a * w1.x;  acc[5]  += a * w1.y;  acc[6]  += a * w1.z;  acc[7]  += a * w1.w;
        acc[8]  += a * w2v.x; acc[9]  += a * w2v.y; acc[10] += a * w2v.z; acc[11] += a * w2v.w;
        acc[12] += a * w3.x;  acc[13] += a * w3.y;  acc[14] += a * w3.z;  acc[15] += a * w3.w;
    }
    unsigned* orow = (unsigned*)(outp + ((size_t)b * 4096 + hw0 + tx2) * 64 + ty2 * 16);
    uint4 o0, o1;
    o0.x = pk2(acc[0], acc[1]);   o0.y = pk2(acc[2], acc[3]);
    o0.z = pk2(acc[4], acc[5]);   o0.w = pk2(acc[6], acc[7]);
    o1.x = pk2(acc[8], acc[9]);   o1.y = pk2(acc[10], acc[11]);
    o1.z = pk2(acc[12], acc[13]); o1.w = pk2(acc[14], acc[15]);
    ((uint4*)orow)[0] = o0;
    ((uint4*)orow)[1] = o1;
}

// ---------------------------------------------------------------------------
// Kernel 2: qk = LN(concat(x,ctx),192); vv = LN(x,128);
// q=(qk@q_w+q_b)*0.25, k=qk@k_w+k_b, v=vv@v_w+v_b -> (B,8,HW,16) bf16 each.
// 16 rows/block (weights amortized 16x). grid 4096, block 256.
// ---------------------------------------------------------------------------
__global__ __launch_bounds__(256) void k_qkv(const float* __restrict__ x,
                                             const bf16* __restrict__ ctxp,
                                             const float* __restrict__ n1g, const float* __restrict__ n1b,
                                             const float* __restrict__ nvg, const float* __restrict__ nvb,
                                             const float* __restrict__ qw, const float* __restrict__ qb,
                                             const float* __restrict__ kw, const float* __restrict__ kb,
                                             const float* __restrict__ vw, const float* __restrict__ vb,
                                             bf16* __restrict__ qo, bf16* __restrict__ ko,
                                             bf16* __restrict__ vo) {
    __shared__ float qkn[16][192];
    __shared__ float vvn[16][128];
    const int t  = threadIdx.x;
    const int r  = t >> 4;          // row in tile
    const int li = t & 15;          // lane within row group
    const int row0 = blockIdx.x * 16;
    {
        const float* xr = x + (size_t)(row0 + r) * 128;
        const bf16*  cr = ctxp + (size_t)(row0 + r) * 64;
        float xv[8], cv[4];
        float s1 = 0.f, s2 = 0.f;
#pragma unroll
        for (int k = 0; k < 8; ++k) { float v = xr[li + 16 * k]; xv[k] = v; s1 += v; s2 += v * v; }
        float t1 = s1, t2 = s2;
#pragma unroll
        for (int k = 0; k < 4; ++k) { float v = b2f(cr[li + 16 * k]); cv[k] = v; s1 += v; s2 += v * v; }
#pragma unroll
        for (int o = 1; o < 16; o <<= 1) {
            s1 += __shfl_xor(s1, o); s2 += __shfl_xor(s2, o);
            t1 += __shfl_xor(t1, o); t2 += __shfl_xor(t2, o);
        }
        float mu  = s1 * (1.f / 192.f);
        float rs  = rsqrtf(s2 * (1.f / 192.f) - mu * mu + 1e-5f);
        float muv = t1 * (1.f / 128.f);
        float rsv = rsqrtf(t2 * (1.f / 128.f) - muv * muv + 1e-5f);
#pragma unroll
        for (int k = 0; k < 8; ++k) {
            int c = li + 16 * k;
            qkn[r][c] = (xv[k] - mu) * rs * n1g[c] + n1b[c];
            vvn[r][c] = (xv[k] - muv) * rsv * nvg[c] + nvb[c];
        }
#pragma unroll
        for (int k = 0; k < 4; ++k) {
            int c = 128 + li + 16 * k;
            qkn[r][c] = (cv[k] - mu) * rs * n1g[c] + n1b[c];
        }
    }
    __syncthreads();
    const int c    = t & 127;       // output channel
    const int half = t >> 7;        // rows half*8 .. +8
    const int head = c >> 4;
    const int d    = c & 15;
    float acc[8];
    // ---- q ----
    {
        float bv = qb[c];
#pragma unroll
        for (int j = 0; j < 8; ++j) acc[j] = bv;
        for (int e = 0; e < 192; e += 4) {
            float w0 = qw[(e + 0) * 128 + c];
            float w1 = qw[(e + 1) * 128 + c];
            float w2v = qw[(e + 2) * 128 + c];
            float w3 = qw[(e + 3) * 128 + c];
#pragma unroll
            for (int j = 0; j < 8; ++j) {
                float4 nv = *(const float4*)&qkn[half * 8 + j][e];
                acc[j] += nv.x * w0 + nv.y * w1 + nv.z * w2v + nv.w * w3;
            }
        }
#pragma unroll
        for (int j = 0; j < 8; ++j) {
            int rowj = row0 + half * 8 + j;
            int b = rowj >> 12, hw = rowj & 4095;
            qo[(((size_t)b * 8 + head) * 4096 + hw) * 16 + d] = f2b(acc[j] * 0.25f);
        }
    }
    // ---- k ----
    {
        float bv = kb[c];
#pragma unroll
        for (int j = 0; j < 8; ++j) acc[j] = bv;
        for (int e = 0; e < 192; e += 4) {
            float w0 = kw[(e + 0) * 128 + c];
            float w1 = kw[(e + 1) * 128 + c];
            float w2v = kw[(e + 2) * 128 + c];
            float w3 = kw[(e + 3) * 128 + c];
#pragma unroll
            for (int j = 0; j < 8; ++j) {
                float4 nv = *(const float4*)&qkn[half * 8 + j][e];
                acc[j] += nv.x * w0 + nv.y * w1 + nv.z * w2v + nv.w * w3;
            }
        }
#pragma unroll
        for (int j = 0; j < 8; ++j) {
            int rowj = row0 + half * 8 + j;
            int b = rowj >> 12, hw = rowj & 4095;
            ko[(((size_t)b * 8 + head) * 4096 + hw) * 16 + d] = f2b(acc[j]);
        }
    }
    // ---- v ----
    {
        float bv = vb[c];
#pragma unroll
        for (int j = 0; j < 8; ++j) acc[j] = bv;
        for (int e = 0; e < 128; e += 4) {
            float w0 = vw[(e + 0) * 128 + c];
            float w1 = vw[(e + 1) * 128 + c];
            float w2v = vw[(e + 2) * 128 + c];
            float w3 = vw[(e + 3) * 128 + c];
#pragma unroll
            for (int j = 0; j < 8; ++j) {
                float4 nv = *(const float4*)&vvn[half * 8 + j][e];
                acc[j] += nv.x * w0 + nv.y * w1 + nv.z * w2v + nv.w * w3;
            }
        }
#pragma unroll
        for (int j = 0; j < 8; ++j) {
            int rowj = row0 + half * 8 + j;
            int b = rowj >> 12, hw = rowj & 4095;
            vo[(((size_t)b * 8 + head) * 4096 + hw) * 16 + d] = f2b(acc[j]);
        }
    }
}

// ---------------------------------------------------------------------------
// Kernel 3: neighborhood attention, K=11. One 64-thread block per (b,head,i);
// thread j = query column. k/v window rows staged in LDS (pad 9 -> no bank
// conflicts). Flash-style online softmax over 121 taps with rpb bias.
// o written directly in (B,HW,128) layout. grid 8192.
// ---------------------------------------------------------------------------
__global__ __launch_bounds__(64) void k_attn(const bf16* __restrict__ qws,
                                             const bf16* __restrict__ kws,
                                             const bf16* __restrict__ vws,
                                             const float* __restrict__ rpb,
                                             bf16* __restrict__ ows) {
    __shared__ unsigned kt[11][64][9];
    __shared__ unsigned vt[11][64][9];
    const int i    = blockIdx.x & 63;
    const int bh   = blockIdx.x >> 6;
    const int head = bh & 7;
    const int j    = threadIdx.x;
    int start_i = i - 5; if (start_i < 0) start_i = 0; if (start_i > 53) start_i = 53;
    const unsigned* ku = (const unsigned*)kws;
    const unsigned* vu = (const unsigned*)vws;
    size_t base = ((size_t)bh * 4096 + (size_t)start_i * 64) * 8;
    for (int t = threadIdx.x; t < 5632; t += 64) {
        int a = t >> 9; int rem = t & 511;
        int col = rem >> 3; int d2 = rem & 7;
        kt[a][col][d2] = ku[base + (size_t)a * 512 + rem];
        vt[a][col][d2] = vu[base + (size_t)a * 512 + rem];
    }
    __syncthreads();
    float qv[16];
    {
        const uint4* qp = (const uint4*)(qws + ((size_t)bh * 4096 + i * 64 + j) * 16);
        uint4 q0 = qp[0], q1 = qp[1];
        qv[0]  = unpk_lo(q0.x); qv[1]  = unpk_hi(q0.x);
        qv[2]  = unpk_lo(q0.y); qv[3]  = unpk_hi(q0.y);
        qv[4]  = unpk_lo(q0.z); qv[5]  = unpk_hi(q0.z);
        qv[6]  = unpk_lo(q0.w); qv[7]  = unpk_hi(q0.w);
        qv[8]  = unpk_lo(q1.x); qv[9]  = unpk_hi(q1.x);
        qv[10] = unpk_lo(q1.y); qv[11] = unpk_hi(q1.y);
        qv[12] = unpk_lo(q1.z); qv[13] = unpk_hi(q1.z);
        qv[14] = unpk_lo(q1.w); qv[15] = unpk_hi(q1.w);
    }
    int start_j = j - 5; if (start_j < 0) start_j = 0; if (start_j > 53) start_j = 53;
    float m = -1e30f, l = 0.f;
    float acc[16];
#pragma unroll
    for (int d = 0; d < 16; ++d) acc[d] = 0.f;
    const float* rpb_h = rpb + head * 441 + (start_j - j + 10);
    for (int a = 0; a < 11; ++a) {
        int ii = start_i + a;
        const float* rb = rpb_h + (ii - i + 10) * 21;
#pragma unroll
        for (int c = 0; c < 11; ++c) {
            int jj = start_j + c;
            const unsigned* kp = kt[a][jj];
            float s = rb[c];
#pragma unroll
            for (int d2 = 0; d2 < 8; ++d2) {
                unsigned u = kp[d2];
                s += qv[2 * d2] * unpk_lo(u) + qv[2 * d2 + 1] * unpk_hi(u);
            }
            float mn   = fmaxf(m, s);
            float corr = __expf(m - mn);
            float p    = __expf(s - mn);
            l = l * corr + p;
            const unsigned* vp = vt[a][jj];
#pragma unroll
            for (int d2 = 0; d2 < 8; ++d2) {
                unsigned u = vp[d2];
                acc[2 * d2]     = acc[2 * d2] * corr     + p * unpk_lo(u);
                acc[2 * d2 + 1] = acc[2 * d2 + 1] * corr + p * unpk_hi(u);
            }
            m = mn;
        }
    }
    float inv = 1.f / l;
    int b = bh >> 3;
    unsigned* op = (unsigned*)ows + ((size_t)b * 4096 + i * 64 + j) * 64 + head * 8;
#pragma unroll
    for (int d2 = 0; d2 < 8; ++d2)
        op[d2] = pk2(acc[2 * d2] * inv, acc[2 * d2 + 1] * inv);
}

// ---------------------------------------------------------------------------
// Kernel 4: y = x + concat(o, x) @ proj_w + proj_b -> fp32 ws.
// 16 rows/block. grid 4096, block 256.
// ---------------------------------------------------------------------------
__global__ __launch_bounds__(256) void k_proj(const float* __restrict__ x,
                                              const bf16* __restrict__ ows,
                                              const float* __restrict__ pw,
                                              const float* __restrict__ pb,
                                              float* __restrict__ yws) {
    __shared__ float inb[16][256];
    const int t = threadIdx.x;
    const size_t row0 = (size_t)blockIdx.x * 16;
    for (int idx = t; idx < 2048; idx += 256) {
        int r = idx >> 7, c2 = idx & 127;
        inb[r][c2] = b2f(ows[(row0 + r) * 128 + c2]);
    }
    for (int idx = t; idx < 2048; idx += 256) {
        int r = idx >> 7, c2 = idx & 127;
        inb[r][128 + c2] = x[(row0 + r) * 128 + c2];
    }
    __syncthreads();
    const int c = t & 127, half = t >> 7;
    float acc[8];
    float bv = pb[c];
#pragma unroll
    for (int j = 0; j < 8; ++j) acc[j] = bv;
    for (int e = 0; e < 256; e += 4) {
        float w0 = pw[(e + 0) * 128 + c];
        float w1 = pw[(e + 1) * 128 + c];
        float w2v = pw[(e + 2) * 128 + c];
        float w3 = pw[(e + 3) * 128 + c];
#pragma unroll
        for (int j = 0; j < 8; ++j) {
            float4 nv = *(const float4*)&inb[half * 8 + j][e];
            acc[j] += nv.x * w0 + nv.y * w1 + nv.z * w2v + nv.w * w3;
        }
    }
#pragma unroll
    for (int j = 0; j < 8; ++j) {
        size_t rowj = row0 + half * 8 + j;
        yws[rowj * 128 + c] = x[rowj * 128 + c] + acc[j];
    }
}

// ---------------------------------------------------------------------------
// Kernel 5: ffn = gelu(LN(y)@f1+b1)@f2+b2; out = fp32(y + ffn).
// 16 rows/block. grid 4096, block 256. LDS: nrm 8K + hb 32K + ybuf 8K = 48K.
// ---------------------------------------------------------------------------
__global__ __launch_bounds__(256) void k_ffn(const float* __restrict__ yws,
                                             const float* __restrict__ g, const float* __restrict__ bb,
                                             const float* __restrict__ w1, const float* __restrict__ b1,
                                             const float* __restrict__ w2, const float* __restrict__ b2,
                                             float* __restrict__ outp) {
    __shared__ float nrm[16][128];
    __shared__ float hb[16][512];
    __shared__ float ybuf[16][128];
    const int t  = threadIdx.x;
    const int r  = t >> 4;
    const int li = t & 15;
    const size_t row0 = (size_t)blockIdx.x * 16;
    {
        const float* yr = yws + (row0 + r) * 128;
        float v[8];
        float s1 = 0.f, s2 = 0.f;
#pragma unroll
        for (int k = 0; k < 8; ++k) { float vv = yr[li + 16 * k]; v[k] = vv; s1 += vv; s2 += vv * vv; }
#pragma unroll
        for (int o = 1; o < 16; o <<= 1) { s1 += __shfl_xor(s1, o); s2 += __shfl_xor(s2, o); }
        float mu = s1 * (1.f / 128.f);
        float rs = rsqrtf(s2 * (1.f / 128.f) - mu * mu + 1e-5f);
#pragma unroll
        for (int k = 0; k < 8; ++k) {
            int c = li + 16 * k;
            nrm[r][c]  = (v[k] - mu) * rs * g[c] + bb[c];
            ybuf[r][c] = v[k];
        }
    }
    __syncthreads();
    // f1 + gelu: thread -> cols c0 = t, c1 = t+256; all 16 rows
    {
        float acc0[16], acc1[16];
        float bv0 = b1[t], bv1 = b1[t + 256];
#pragma unroll
        for (int j = 0; j < 16; ++j) { acc0[j] = bv0; acc1[j] = bv1; }
        for (int e = 0; e < 128; e += 4) {
            float wa0 = w1[(e + 0) * 512 + t],       wa1 = w1[(e + 1) * 512 + t];
            float wa2 = w1[(e + 2) * 512 + t],       wa3 = w1[(e + 3) * 512 + t];
            float wb0 = w1[(e + 0) * 512 + t + 256], wb1 = w1[(e + 1) * 512 + t + 256];
            float wb2 = w1[(e + 2) * 512 + t + 256], wb3 = w1[(e + 3) * 512 + t + 256];
#pragma unroll
            for (int j = 0; j < 16; ++j) {
                float4 nv = *(const float4*)&nrm[j][e];
                acc0[j] += nv.x * wa0 + nv.y * wa1 + nv.z * wa2 + nv.w * wa3;
                acc1[j] += nv.x * wb0 + nv.y * wb1 + nv.z * wb2 + nv.w * wb3;
            }
        }
        __syncthreads();
#pragma unroll
        for (int j = 0; j < 16; ++j) {
            hb[j][t]       = gelu_exact(acc0[j]);
            hb[j][t + 256] = gelu_exact(acc1[j]);
        }
    }
    __syncthreads();
    // f2: thread -> col c = t&127, rows half*8..+8
    {
        const int c = t & 127, half = t >> 7;
        float acc[8];
#pragma unroll
        for (int j = 0; j < 8; ++j) acc[j] = 0.f;
        for (int f = 0; f < 512; f += 4) {
            float w0 = w2[(f + 0) * 128 + c];
            float w1v = w2[(f + 1) * 128 + c];
            float w2v = w2[(f + 2) * 128 + c];
            float w3 = w2[(f + 3) * 128 + c];
#pragma unroll
            for (int j = 0; j < 8; ++j) {
                float4 hv = *(const float4*)&hb[half * 8 + j][f];
                acc[j] += hv.x * w0 + hv.y * w1v + hv.z * w2v + hv.w * w3;
            }
        }
        float bv = b2[c];
#pragma unroll
        for (int j = 0; j < 8; ++j) {
            size_t rowj = row0 + half * 8 + j;
            outp[rowj * 128 + c] = ybuf[half * 8 + j][c] + acc[j] + bv;
        }
    }
}

extern "C" void kernel_launch(void* const* d_in, const int* in_sizes, int n_in,
                              void* d_out, int out_size, void* d_ws, size_t ws_size,
                              hipStream_t stream) {
    const float* x      = (const float*)d_in[0];
    const float* ctx    = (const float*)d_in[1];
    const float* ctxn_g = (const float*)d_in[2];
    const float* ctxn_b = (const float*)d_in[3];
    const float* ctxp_w = (const float*)d_in[4];
    const float* ctxp_b = (const float*)d_in[5];
    const float* n1_g   = (const float*)d_in[6];
    const float* n1_b   = (const float*)d_in[7];
    const float* n1v_g  = (const float*)d_in[8];
    const float* n1v_b  = (const float*)d_in[9];
    const float* q_w    = (const float*)d_in[10];
    const float* q_b    = (const float*)d_in[11];
    const float* k_w    = (const float*)d_in[12];
    const float* k_b    = (const float*)d_in[13];
    const float* v_w    = (const float*)d_in[14];
    const float* v_b    = (const float*)d_in[15];
    const float* rpb    = (const float*)d_in[16];
    const float* proj_w = (const float*)d_in[17];
    const float* proj_b = (const float*)d_in[18];
    const float* n2_g   = (const float*)d_in[19];
    const float* n2_b   = (const float*)d_in[20];
    const float* f1_w   = (const float*)d_in[21];
    const float* f1_b   = (const float*)d_in[22];
    const float* f2_w   = (const float*)d_in[23];
    const float* f2_b   = (const float*)d_in[24];
    float* out = (float*)d_out;

    char* ws = (char*)d_ws;
    bf16*  ctxp = (bf16*)(ws);                    //  8,388,608 B  (B,HW,64)  bf16
    bf16*  qws  = (bf16*)(ws + 8388608);          // 16,777,216 B  (B,8,HW,16) bf16
    bf16*  kws  = (bf16*)(ws + 25165824);         // 16,777,216 B
    bf16*  vws  = (bf16*)(ws + 41943040);         // 16,777,216 B
    bf16*  ows  = (bf16*)(ws + 58720256);         // 16,777,216 B  (B,HW,128) bf16
    float* yws  = (float*)(ws + 75497472);        // 33,554,432 B  (B,HW,128) fp32
    // total 109,051,904 B

    k_ctx<<<1024, 256, 0, stream>>>(ctx, ctxn_g, ctxn_b, ctxp_w, ctxp_b, ctxp);
    k_qkv<<<4096, 256, 0, stream>>>(x, ctxp, n1_g, n1_b, n1v_g, n1v_b,
                                    q_w, q_b, k_w, k_b, v_w, v_b, qws, kws, vws);
    k_attn<<<8192, 64, 0, stream>>>(qws, kws, vws, rpb, ows);
    k_proj<<<4096, 256, 0, stream>>>(x, ows, proj_w, proj_b, yws);
    k_ffn<<<4096, 256, 0, stream>>>(yws, n2_g, n2_b, f1_w, f1_b, f2_w, f2_b, out);
}